// Round 10
// baseline (63.639 us; speedup 1.0000x reference)
//
#include <hip/hip_runtime.h>

#define N_TOK 131072
#define DIM 64
#define K_CODES 1024
#define ALPHA 0.9f
#define ROWS 256                  // tokens per block
#define NBLK (N_TOK / ROWS)       // 512 blocks = 2 per CU, single generation
#define NTILE (ROWS / 16)         // 16 row-tiles per block
#define WCODES 128                // codes per wave (8 waves x 128 = 1024)

typedef short bf16x8 __attribute__((ext_vector_type(8)));
typedef float f32x4  __attribute__((ext_vector_type(4)));
typedef int   i32x4  __attribute__((ext_vector_type(4)));

__device__ __forceinline__ short f2bf(float f) {
    unsigned u = __builtin_bit_cast(unsigned, f);
    u += 0x7fffu + ((u >> 16) & 1u);
    return (short)(u >> 16);
}
__device__ __forceinline__ unsigned umin2(unsigned a, unsigned b) { return a < b ? a : b; }
__device__ __forceinline__ int cvtpk(float a, float b) {
    int r;
    asm("v_cvt_pk_bf16_f32 %0, %1, %2" : "=v"(r) : "v"(a), "v"(b));
    return r;
}

// ---------------- prep: Wb = bf16 (linear), w2p3[k] = 3 + ||w_k||^2 ----------------
__global__ __launch_bounds__(256) void prep_kernel(const float* __restrict__ W,
                                                   short* __restrict__ Wb,
                                                   float* __restrict__ w2p3) {
    int u = blockIdx.x * 256 + threadIdx.x;      // 0..8191 : one 16B bf16 group each
    const float4* s = (const float4*)(W + (size_t)u * 8);
    float4 a = s[0], b = s[1];
    bf16x8 v = { f2bf(a.x), f2bf(a.y), f2bf(a.z), f2bf(a.w),
                 f2bf(b.x), f2bf(b.y), f2bf(b.z), f2bf(b.w) };
    *(bf16x8*)(Wb + (size_t)u * 8) = v;

    if (u < K_CODES) {
        const float4* wr = (const float4*)(W + (size_t)u * DIM);
        float sacc = 0.f;
#pragma unroll
        for (int i = 0; i < DIM / 4; ++i) {
            float4 t = wr[i];
            sacc += t.x * t.x + t.y * t.y + t.z * t.z + t.w * t.w;
        }
        w2p3[u] = 3.0f + sacc;
    }
}

// ---------------- main fused kernel: B in registers, stream x, no main-loop LDS/barriers ----
__global__ __launch_bounds__(512, 4) void vq_kernel(const float* __restrict__ x,
                                                    const float* __restrict__ W,
                                                    const short* __restrict__ Wb,
                                                    const float* __restrict__ w2p3,
                                                    float* __restrict__ out,
                                                    float* __restrict__ blocksum) {
    __shared__ unsigned red[8][ROWS];   // 8 KB: per-wave per-row packed minima
    __shared__ int      jrow[ROWS];     // 1 KB
    __shared__ float    wavesum[8];

    const int t    = threadIdx.x;
    const int wv   = t >> 6;            // wave 0..7: owns codes [wv*128, +128)
    const int lane = t & 63;
    const int l15  = t & 15;
    const int lg   = lane >> 4;
    const int row0 = blockIdx.x * ROWS;

    // ---- B fragments for this wave's 128 codes: 16 x dwordx4 from L2, once ----
    bf16x8 barr[8][2];
    const short* wl = Wb + ((wv * WCODES + l15) * DIM + lg * 8);
#pragma unroll
    for (int ct = 0; ct < 8; ++ct) {
        const short* wp = wl + ct * 16 * DIM;
        barr[ct][0] = *(const bf16x8*)wp;         // k  0..31 slice (this lg)
        barr[ct][1] = *(const bf16x8*)(wp + 32);  // k 32..63 slice
    }
    // ---- C-init: acc = dot - w2/2 - 1.5  (so final acc in (-2,-1): fixed exponent) ----
    float cinit[8];
#pragma unroll
    for (int ct = 0; ct < 8; ++ct)
        cinit[ct] = -0.5f * w2p3[wv * WCODES + ct * 16 + l15];

    const unsigned kbase = (unsigned)(wv * WCODES + l15);
    const float* xrow = x + (size_t)(row0 + l15) * DIM + lg * 8;
    float x2part = 0.f;

#pragma unroll 1
    for (int tile = 0; tile < NTILE; ++tile) {
        // x tile: lane = (row l15, cols lg*8.. & 32+lg*8..)
        float4 f0 = *(const float4*)xrow;
        float4 f1 = *(const float4*)(xrow + 4);
        float4 f2 = *(const float4*)(xrow + 32);
        float4 f3 = *(const float4*)(xrow + 36);
        xrow += 16 * DIM;

        if (wv == 0) {   // sum x^2 exactly once chip-wide
            x2part += f0.x*f0.x + f0.y*f0.y + f0.z*f0.z + f0.w*f0.w
                    + f1.x*f1.x + f1.y*f1.y + f1.z*f1.z + f1.w*f1.w
                    + f2.x*f2.x + f2.y*f2.y + f2.z*f2.z + f2.w*f2.w
                    + f3.x*f3.x + f3.y*f3.y + f3.z*f3.z + f3.w*f3.w;
        }

        i32x4 p0 = { cvtpk(f0.x, f0.y), cvtpk(f0.z, f0.w), cvtpk(f1.x, f1.y), cvtpk(f1.z, f1.w) };
        i32x4 p1 = { cvtpk(f2.x, f2.y), cvtpk(f2.z, f2.w), cvtpk(f3.x, f3.y), cvtpk(f3.z, f3.w) };
        bf16x8 a0 = __builtin_bit_cast(bf16x8, p0);
        bf16x8 a1 = __builtin_bit_cast(bf16x8, p1);

        unsigned best[4] = { 0xFFFFFFFFu, 0xFFFFFFFFu, 0xFFFFFFFFu, 0xFFFFFFFFu };
#pragma unroll
        for (int ct = 0; ct < 8; ++ct) {
            float ci = cinit[ct];
            f32x4 acc = { ci, ci, ci, ci };
            acc = __builtin_amdgcn_mfma_f32_16x16x32_bf16(a0, barr[ct][0], acc, 0, 0, 0);
            acc = __builtin_amdgcn_mfma_f32_16x16x32_bf16(a1, barr[ct][1], acc, 0, 0, 0);
            unsigned kidx = kbase + ct * 16;
            // C layout: col = lane&15 (= code), row-in-tile = lg*4 + j; acc < 0 always,
            // more-negative = worse -> umin on raw bits picks best score, low bits = k
#pragma unroll
            for (int j = 0; j < 4; ++j) {
                unsigned pk = (__builtin_bit_cast(unsigned, acc[j]) & 0xFFFFFC00u) | kidx;
                best[j] = umin2(best[j], pk);
            }
        }

        // reduce over the 16 codes held across l15 lanes; rows distinct per (lg, j)
#pragma unroll
        for (int j = 0; j < 4; ++j) {
            unsigned v = best[j];
            v = umin2(v, (unsigned)__shfl_xor((int)v, 1));
            v = umin2(v, (unsigned)__shfl_xor((int)v, 2));
            v = umin2(v, (unsigned)__shfl_xor((int)v, 4));
            v = umin2(v, (unsigned)__shfl_xor((int)v, 8));
            if (l15 == 0) red[wv][tile * 16 + lg * 4 + j] = v;
        }
    }

    __syncthreads();   // first barrier in the kernel

    // ---- cross-wave reduce + loss ----
    float psum = x2part;               // nonzero only on wave 0
    if (t < ROWS) {
        unsigned m = red[0][t];
#pragma unroll
        for (int q = 1; q < 8; ++q) m = umin2(m, red[q][t]);
        jrow[t] = (int)(m & 1023u);
        float a = __builtin_bit_cast(float, m & 0xFFFFFC00u);   // acc (quantized)
        psum += fmaf(-2.f, a, -3.0f);                            // s = -2*acc - 3 = w2 - 2dot
    }
    __syncthreads();

    // ---- gather W[j] fp32 (L2-hot) -> out: 2 threads per row, 128B each ----
    {
        int r = t >> 1, h = t & 1;
        int j = jrow[r];
        const float4* wr = (const float4*)(W + (size_t)j * DIM) + h * 8;
        float4* od = (float4*)(out + (size_t)(row0 + r) * DIM) + h * 8;
#pragma unroll
        for (int i = 0; i < 8; ++i) od[i] = wr[i];
    }

    // ---- block-reduce loss partial (8 waves) ----
#pragma unroll
    for (int off = 32; off; off >>= 1) psum += __shfl_down(psum, off);
    if (lane == 0) wavesum[wv] = psum;
    __syncthreads();
    if (t == 0) {
        float s = 0.f;
#pragma unroll
        for (int i = 0; i < 8; ++i) s += wavesum[i];
        blocksum[blockIdx.x] = s;
    }
}

// ---------------- deterministic finish ----------------
__global__ __launch_bounds__(256) void finish_kernel(const float* __restrict__ bs,
                                                     float* __restrict__ out) {
    __shared__ float wavesum[4];
    int t = threadIdx.x;
    float s = 0.f;
    for (int i = t; i < NBLK; i += 256) s += bs[i];
#pragma unroll
    for (int off = 32; off; off >>= 1) s += __shfl_down(s, off);
    if ((t & 63) == 0) wavesum[t >> 6] = s;
    __syncthreads();
    if (t == 0)
        out[(size_t)N_TOK * DIM] = (wavesum[0] + wavesum[1] + wavesum[2] + wavesum[3]) *
                                   ((1.0f + ALPHA) / (float)N_TOK);
}

extern "C" void kernel_launch(void* const* d_in, const int* in_sizes, int n_in,
                              void* d_out, int out_size, void* d_ws, size_t ws_size,
                              hipStream_t stream) {
    const float* x = (const float*)d_in[0];
    const float* W = (const float*)d_in[1];
    float* out = (float*)d_out;
    float* ws  = (float*)d_ws;

    float* blocksum = ws;                   // 512 floats
    float* w2p3     = ws + 2048;            // 1024 floats
    short* Wb       = (short*)(ws + 3072);  // 65536 bf16 = 128 KB (linear)

    prep_kernel<<<32, 256, 0, stream>>>(W, Wb, w2p3);
    vq_kernel<<<NBLK, 512, 0, stream>>>(x, W, Wb, w2p3, out, blocksum);
    finish_kernel<<<1, 256, 0, stream>>>(blocksum, out);
}